// Round 15
// baseline (657.322 us; speedup 1.0000x reference)
//
#include <hip/hip_runtime.h>
#include <math.h>

#define B_   32
#define L_   2048
#define DSEQ 1024
#define DGLB 1024
#define H_   16
#define DK_  64
#define DV_  64
#define LT   64
#define NT   (L_/LT)      // 32
#define PSTRIDE 66        // m, s, y[64]

// Wc2 layout: [h][ks(32)][j(128)][e(32)] bf16; d = ks*32 + e
#define WC_KSTRIDE 4096            // 128*32 elems per k-step
#define WC_HSTRIDE 131072          // 32*4096 elems per head

#define AS1 __attribute__((address_space(1)))
#define AS3 __attribute__((address_space(3)))

using u16    = unsigned short;
using bf16x8 = __attribute__((ext_vector_type(8))) short;
using f32x4  = __attribute__((ext_vector_type(4))) float;

__device__ __forceinline__ u16 f2bf(float x) {
  union { float f; unsigned int u; } v; v.f = x;
  return (u16)((v.u + 0x7fffu + ((v.u >> 16) & 1u)) >> 16);   // RNE
}

__device__ __forceinline__ float tanh_fast(float x) {
  float e = __builtin_exp2f(x * 2.885390081777927f);   // 2*log2(e)
  return 1.f - 2.f/(e + 1.f);
}

__device__ __forceinline__ float erf_fast(float x) {
  float ax = fabsf(x);
  float t  = 1.f/(1.f + 0.3275911f*ax);
  float p  = t*(0.254829592f + t*(-0.284496736f + t*(1.421413741f +
             t*(-1.453152027f + t*1.061405429f))));
  float e  = __builtin_exp2f(-ax*ax*1.4426950408889634f);  // e^{-x^2}
  float r  = 1.f - p*e;
  return copysignf(r, x);
}

#define PHASE_BARRIER(N)                                   \
  do {                                                     \
    __builtin_amdgcn_sched_barrier(0);                     \
    asm volatile("s_waitcnt vmcnt(" #N ")" ::: "memory");  \
    __builtin_amdgcn_s_barrier();                          \
    __builtin_amdgcn_sched_barrier(0);                     \
  } while (0)

// Wc2[h][d>>5][j][d&31]: j<64 -> Wk[h,:,j], else Wv[h,:,j-64]
__global__ void pack_w_kernel(const float* __restrict__ Wk,
                              const float* __restrict__ Wv,
                              u16* __restrict__ Wc) {
  const int h = blockIdx.x, j = blockIdx.y;
  const float* src = (j < DK_) ? (Wk + (size_t)h*DSEQ*DK_ + j)
                               : (Wv + (size_t)h*DSEQ*DV_ + (j - DK_));
  u16* dst = Wc + (size_t)h*WC_HSTRIDE + (size_t)j*32;
  for (int d = threadIdx.x; d < DSEQ; d += blockDim.x)
    dst[(size_t)(d >> 5)*WC_KSTRIDE + (d & 31)] = f2bf(src[(size_t)d*64]);
}

// S (fp32) -> Sb (bf16), flat; 8-elem granules, coalesced
__global__ void s2bf_kernel(const float* __restrict__ S, u16* __restrict__ Sb) {
  const size_t G = (size_t)B_*L_*DSEQ/8;
  for (size_t i = (size_t)blockIdx.x*256 + threadIdx.x; i < G; i += (size_t)4096*256) {
    const float4* sp = (const float4*)(S + i*8);
    float4 v0 = sp[0], v1 = sp[1];
    bf16x8 wv;
    wv[0]=(short)f2bf(v0.x); wv[1]=(short)f2bf(v0.y);
    wv[2]=(short)f2bf(v0.z); wv[3]=(short)f2bf(v0.w);
    wv[4]=(short)f2bf(v1.x); wv[5]=(short)f2bf(v1.y);
    wv[6]=(short)f2bf(v1.z); wv[7]=(short)f2bf(v1.w);
    *(bf16x8*)(Sb + i*8) = wv;
  }
}

// Q[b][h][k] = tanh(sum_d X[b,d]*Wq[h,d,k]); grid (H, B/4), block 64
__global__ void q_proj_kernel(const float* __restrict__ X,
                              const float* __restrict__ Wq,
                              float* __restrict__ Q) {
  const int h = blockIdx.x, b0 = blockIdx.y*4, k = threadIdx.x;
  const float* w = Wq + (size_t)h*DGLB*DK_ + k;
  float a0=0.f, a1=0.f, a2=0.f, a3=0.f;
  for (int d = 0; d < DGLB; ++d) {
    float wv = w[(size_t)d*DK_];
    a0 += X[(size_t)(b0+0)*DGLB + d]*wv;
    a1 += X[(size_t)(b0+1)*DGLB + d]*wv;
    a2 += X[(size_t)(b0+2)*DGLB + d]*wv;
    a3 += X[(size_t)(b0+3)*DGLB + d]*wv;
  }
  Q[((size_t)(b0+0)*H_+h)*DK_+k] = tanhf(a0);
  Q[((size_t)(b0+1)*H_+h)*DK_+k] = tanhf(a1);
  Q[((size_t)(b0+2)*H_+h)*DK_+k] = tanhf(a2);
  Q[((size_t)(b0+3)*H_+h)*DK_+k] = tanhf(a3);
}

// grid: 4096 linear blocks, 256 threads = 4 waves, 3 blocks/CU (r12 shape).
// slot=id&7 -> XCD; grp=slot>>1 -> head-GROUP (4 heads = 2 pairs).
// Each block stages its 64-row A tile ONCE per subtile round and runs TWO
// sequential passes (head-pairs grp*2, grp*2+1): pass-1 A-staging re-reads
// bytes this block just pulled -> own-XCD L2/L3 hits (A HBM traffic halves).
// 16-phase continuous pipeline: 3 x 16 KB LDS buffers, stage(s+2) issue-
// early, counted PHASE_BARRIER (in-flight prefetch never drained).
// B rolling pointer wraps into the NEXT pair's base at kstep 31, so pass-1
// B-init loads issue during phase 7 and land under the pass-0 epilogue.
// Head math: h = grp*4 + pass*2 + hp; wb base = head grp*4+hp (hp stride =
// ONE head; r14 bug was hp*2 -> wrong heads + OOB read past Wc -> NaN).
template<int BF16SRC>
__global__ __launch_bounds__(256, 3) void fused_kernel(
    const float* __restrict__ S, const u16* __restrict__ Sb,
    const u16* __restrict__ Wc, const float* __restrict__ Q,
    float* __restrict__ part) {
  __shared__ u16   Slds[3*64*128];   // 3 x 16 KB, rows 256 B
  __shared__ float lpart[2][64];

  const int id   = blockIdx.x;
  const int slot = id & 7;           // XCD
  const int grp  = slot >> 1;        // head group (heads 4g..4g+3)
  const int m    = id >> 3;          // 0..511
  const int tile = (((m + (grp << 7)) & 511) << 1) | (slot & 1);  // 0..1023
  const int t    = tile & (NT-1), b = tile >> 5;

  const int tid  = threadIdx.x;
  const int wave = tid >> 6, lane = tid & 63;
  const int lhi  = lane >> 4, llo = lane & 15;
  const int isV  = wave & 1,  hp  = wave >> 1;

  int arow[4];
  #pragma unroll
  for (int rt = 0; rt < 4; ++rt) arow[rt] = (rt*16 + llo)*256;  // bytes

  const u16*   Sv = Sb + ((size_t)b*L_ + (size_t)t*LT)*DSEQ;
  const float* Sf = S  + ((size_t)b*L_ + (size_t)t*LT)*DSEQ;

  // stage sub-tile ((sub&7): 64 rows x 128 k = 16 KB) into buf[sub%3]
  auto stage_gl = [&](int sub) {
    const int bs = (sub % 3) * 8192;           // u16 offset (16 KB)
    const int ko = (sub & 7) * 128;
    #pragma unroll
    for (int it = 0; it < 4; ++it) {
      const int j   = wave*4 + it;
      const int row = 4*j + (lane >> 4);
      const int g   = (lane & 15) ^ (row & 15);
      const u16* gp = Sv + (size_t)row*DSEQ + ko + (g << 3);
      __builtin_amdgcn_global_load_lds(
          (const AS1 void*)gp, (AS3 void*)(Slds + bs + j*512), 16, 0, 0);
    }
  };
  auto stage_reg = [&](int sub) {              // fp32 fallback
    const int bs = (sub % 3) * 16384;          // bytes
    const int ko = (sub & 7) * 128;
    #pragma unroll
    for (int it = 0; it < 4; ++it) {
      int f = it*256 + tid, row = f >> 4, q = f & 15;
      int g = q ^ (row & 15);
      const float4* sp = (const float4*)(Sf + (size_t)row*DSEQ + ko + g*8);
      float4 v0 = sp[0], v1 = sp[1];
      bf16x8 wv;
      wv[0]=(short)f2bf(v0.x); wv[1]=(short)f2bf(v0.y);
      wv[2]=(short)f2bf(v0.z); wv[3]=(short)f2bf(v0.w);
      wv[4]=(short)f2bf(v1.x); wv[5]=(short)f2bf(v1.y);
      wv[6]=(short)f2bf(v1.z); wv[7]=(short)f2bf(v1.w);
      *(bf16x8*)((char*)Slds + bs + row*256 + q*16) = wv;
    }
  };

  // prologue: stage subs 0,1 (pinned first), then B init (pair 0, steps 0..3)
  // head for pass 0, this hp: grp*4 + hp  (hp stride = ONE head)
  const u16* wb = Wc + (size_t)(grp*4 + hp)*WC_HSTRIDE
                     + (size_t)(isV*64 + llo)*32 + lhi*8;
  if (BF16SRC) {
    stage_gl(0);
    stage_gl(1);
    __builtin_amdgcn_sched_barrier(0);
  }
  bf16x8 bA[4], bB[4], bC[4], bD[4];
  #pragma unroll
  for (int c = 0; c < 4; ++c) bA[c] = *(const bf16x8*)(wb + (size_t)0*WC_KSTRIDE + c*512);
  #pragma unroll
  for (int c = 0; c < 4; ++c) bB[c] = *(const bf16x8*)(wb + (size_t)1*WC_KSTRIDE + c*512);
  #pragma unroll
  for (int c = 0; c < 4; ++c) bC[c] = *(const bf16x8*)(wb + (size_t)2*WC_KSTRIDE + c*512);
  #pragma unroll
  for (int c = 0; c < 4; ++c) bD[c] = *(const bf16x8*)(wb + (size_t)3*WC_KSTRIDE + c*512);
  const u16* wbp = wb + (size_t)4*WC_KSTRIDE;  // rolling refill pointer
  if (BF16SRC) PHASE_BARRIER(20);              // stage(0) done; rest in flight

#define KSTEP(BUF, kk)                                                        \
  do {                                                                        \
    const int colb = (((kk)*4 + lhi) ^ llo) << 4;                             \
    __builtin_amdgcn_s_setprio(1);                                            \
    _Pragma("unroll")                                                         \
    for (int rt = 0; rt < 4; ++rt) {                                          \
      bf16x8 af = *(const bf16x8*)(cb + arow[rt] + colb);                     \
      acc[rt][0] = __builtin_amdgcn_mfma_f32_16x16x32_bf16(af, BUF[0], acc[rt][0], 0,0,0); \
      acc[rt][1] = __builtin_amdgcn_mfma_f32_16x16x32_bf16(af, BUF[1], acc[rt][1], 0,0,0); \
      acc[rt][2] = __builtin_amdgcn_mfma_f32_16x16x32_bf16(af, BUF[2], acc[rt][2], 0,0,0); \
      acc[rt][3] = __builtin_amdgcn_mfma_f32_16x16x32_bf16(af, BUF[3], acc[rt][3], 0,0,0); \
    }                                                                         \
    __builtin_amdgcn_s_setprio(0);                                            \
    _Pragma("unroll")                                                         \
    for (int c = 0; c < 4; ++c)                                               \
      BUF[c] = *(const bf16x8*)(wbp + c*512);                                 \
    wbp += ((s8*4 + (kk) + 4) == 31) ? wrapjump : (ptrdiff_t)WC_KSTRIDE;      \
  } while (0)

  for (int pass = 0; pass < 2; ++pass) {
    const int h = grp*4 + pass*2 + hp;
    // kstep-31 refill jump: pass 0 -> next PAIR's same head (+2 heads);
    // pass 1 -> wrap to own step 0 (harmless dead refills)
    const ptrdiff_t wrapjump = (pass == 0)
        ? (ptrdiff_t)2*WC_HSTRIDE - (ptrdiff_t)31*WC_KSTRIDE
        : -(ptrdiff_t)31*WC_KSTRIDE;

    f32x4 acc[4][4];
    #pragma unroll
    for (int rt = 0; rt < 4; ++rt)
      #pragma unroll
      for (int c = 0; c < 4; ++c) acc[rt][c] = {0.f,0.f,0.f,0.f};

    #pragma unroll
    for (int s8 = 0; s8 < 8; ++s8) {
      const int sg = pass*8 + s8;              // global phase 0..15
      if (BF16SRC) {
        if (sg <= 13) { stage_gl(sg + 2); __builtin_amdgcn_sched_barrier(0); }
      } else {
        stage_reg(sg);
        __syncthreads();
      }
      const char* cb = (const char*)Slds + (sg % 3)*16384;
      KSTEP(bA, 0); KSTEP(bB, 1); KSTEP(bC, 2); KSTEP(bD, 3);
      if (BF16SRC) {
        if (sg <= 13)       PHASE_BARRIER(36); // stage(sg+1) done, rest flies
        else if (sg == 14)  PHASE_BARRIER(32);
        // sg == 15: the epilogue __syncthreads covers the final drain
      } else {
        __syncthreads();
      }
    }

    // ---- epilogue for this head-pair ----
    if (!isV) {
      const float* Qb = Q + ((size_t)b*H_ + h)*DK_;
      float q[4];
      #pragma unroll
      for (int c = 0; c < 4; ++c) q[c] = Qb[16*c + llo];
      #pragma unroll
      for (int rt = 0; rt < 4; ++rt) {
        #pragma unroll
        for (int r = 0; r < 4; ++r) {
          float pl = q[0]*tanh_fast(acc[rt][0][r]) + q[1]*tanh_fast(acc[rt][1][r])
                   + q[2]*tanh_fast(acc[rt][2][r]) + q[3]*tanh_fast(acc[rt][3][r]);
          pl += __shfl_xor(pl, 1); pl += __shfl_xor(pl, 2);
          pl += __shfl_xor(pl, 4); pl += __shfl_xor(pl, 8);
          if (llo == 0) lpart[hp][rt*16 + lhi*4 + r] = pl;
        }
      }
    } else {
      #pragma unroll
      for (int rt = 0; rt < 4; ++rt)
        #pragma unroll
        for (int c = 0; c < 4; ++c)
          #pragma unroll
          for (int r = 0; r < 4; ++r) {
            float x = acc[rt][c][r];
            acc[rt][c][r] = 0.5f*x*(1.f + erf_fast(x*0.70710678118654752f));
          }
    }
    __syncthreads();   // lpart ready; also drains in-flight stages (vmcnt 0)

    if (isV) {
      float lg = lpart[hp][lane] * 0.125f;   // 1/sqrt(64)
      float mx = lg;
      #pragma unroll
      for (int mk = 1; mk < 64; mk <<= 1) mx = fmaxf(mx, __shfl_xor(mx, mk));
      float ev = __expf(lg - mx);
      float sv = ev;
      #pragma unroll
      for (int mk = 1; mk < 64; mk <<= 1) sv += __shfl_xor(sv, mk);

      float er[16];
      #pragma unroll
      for (int rt = 0; rt < 4; ++rt)
        #pragma unroll
        for (int r = 0; r < 4; ++r)
          er[rt*4 + r] = __shfl(ev, rt*16 + lhi*4 + r);

      float* pt = part + (((size_t)b*H_ + h)*NT + t)*PSTRIDE;
      #pragma unroll
      for (int c = 0; c < 4; ++c) {
        float y = 0.f;
        #pragma unroll
        for (int rt = 0; rt < 4; ++rt)
          #pragma unroll
          for (int r = 0; r < 4; ++r)
            y += er[rt*4 + r]*acc[rt][c][r];
        y += __shfl_xor(y, 16); y += __shfl_xor(y, 32);
        if (lhi == 0) pt[2 + 16*c + llo] = y;
      }
      if (lane == 0) { pt[0] = mx; pt[1] = sv; }
    }
  }
#undef KSTEP
}

// merge NT tile-partials per (b,h); grid (H, B), block 64
__global__ void finalize_kernel(const float* __restrict__ part,
                                float* __restrict__ out) {
  const int h = blockIdx.x, b = blockIdx.y, v = threadIdx.x;
  const float* p = part + ((size_t)b*H_ + h)*(size_t)NT*PSTRIDE;
  float M = -3.0e38f;
  for (int tt = 0; tt < NT; ++tt) M = fmaxf(M, p[tt*PSTRIDE]);
  float ss = 0.f, y = 0.f;
  for (int tt = 0; tt < NT; ++tt) {
    float w = expf(p[tt*PSTRIDE] - M);
    ss += w*p[tt*PSTRIDE + 1];
    y  += w*p[tt*PSTRIDE + 2 + v];
  }
  out[((size_t)b*H_ + h)*DV_ + v] = y/ss;
}

extern "C" void kernel_launch(void* const* d_in, const int* in_sizes, int n_in,
                              void* d_out, int out_size, void* d_ws, size_t ws_size,
                              hipStream_t stream) {
  const float* X  = (const float*)d_in[0];
  const float* S  = (const float*)d_in[1];
  const float* Wq = (const float*)d_in[2];
  const float* Wk = (const float*)d_in[3];
  const float* Wv = (const float*)d_in[4];
  float* out = (float*)d_out;

  char* ws = (char*)d_ws;
  u16*   Wc    = (u16*)ws;                              // 4 MiB
  float* Qbuf  = (float*)(ws + (4u<<20));               // 128 KiB
  float* part  = (float*)(ws + (4u<<20) + (128u<<10));  // ~4.3 MiB
  u16*   Sb    = (u16*)(ws + (16u<<20));                // 128 MiB (optional)
  const bool useBf = ws_size >= (144ull << 20);

  pack_w_kernel  <<<dim3(H_, 128),  256, 0, stream>>>(Wk, Wv, Wc);
  q_proj_kernel  <<<dim3(H_, B_/4),  64, 0, stream>>>(X, Wq, Qbuf);
  if (useBf) {
    s2bf_kernel       <<<dim3(4096), 256, 0, stream>>>(S, Sb);
    fused_kernel<1>   <<<dim3(4096), 256, 0, stream>>>(S, Sb, Wc, Qbuf, part);
  } else {
    fused_kernel<0>   <<<dim3(4096), 256, 0, stream>>>(S, Sb, Wc, Qbuf, part);
  }
  finalize_kernel<<<dim3(H_, B_),    64, 0, stream>>>(part, out);
}

// Round 16
// 496.652 us; speedup vs baseline: 1.3235x; 1.3235x over previous
//
#include <hip/hip_runtime.h>
#include <math.h>

#define B_   32
#define L_   2048
#define DSEQ 1024
#define DGLB 1024
#define H_   16
#define DK_  64
#define DV_  64
#define NT   32           // 64-row groups per (b,h)
#define PSTRIDE 66        // m, s, y[64]

// Wc2 layout: [h][ks(32)][j(128)][e(32)] bf16; d = ks*32 + e
#define WC_KSTRIDE 4096            // 128*32 elems per k-step
#define WC_HSTRIDE 131072          // 32*4096 elems per head

#define AS1 __attribute__((address_space(1)))
#define AS3 __attribute__((address_space(3)))

using u16    = unsigned short;
using bf16x8 = __attribute__((ext_vector_type(8))) short;
using f32x4  = __attribute__((ext_vector_type(4))) float;

__device__ __forceinline__ u16 f2bf(float x) {
  union { float f; unsigned int u; } v; v.f = x;
  return (u16)((v.u + 0x7fffu + ((v.u >> 16) & 1u)) >> 16);   // RNE
}

__device__ __forceinline__ float tanh_fast(float x) {
  float e = __builtin_exp2f(x * 2.885390081777927f);   // 2*log2(e)
  return 1.f - 2.f/(e + 1.f);
}

__device__ __forceinline__ float erf_fast(float x) {
  float ax = fabsf(x);
  float t  = 1.f/(1.f + 0.3275911f*ax);
  float p  = t*(0.254829592f + t*(-0.284496736f + t*(1.421413741f +
             t*(-1.453152027f + t*1.061405429f))));
  float e  = __builtin_exp2f(-ax*ax*1.4426950408889634f);  // e^{-x^2}
  float r  = 1.f - p*e;
  return copysignf(r, x);
}

#define PHASE_BARRIER(N)                                   \
  do {                                                     \
    __builtin_amdgcn_sched_barrier(0);                     \
    asm volatile("s_waitcnt vmcnt(" #N ")" ::: "memory");  \
    __builtin_amdgcn_s_barrier();                          \
    __builtin_amdgcn_sched_barrier(0);                     \
  } while (0)

// Wc2[h][d>>5][j][d&31]: j<64 -> Wk[h,:,j], else Wv[h,:,j-64]
__global__ void pack_w_kernel(const float* __restrict__ Wk,
                              const float* __restrict__ Wv,
                              u16* __restrict__ Wc) {
  const int h = blockIdx.x, j = blockIdx.y;
  const float* src = (j < DK_) ? (Wk + (size_t)h*DSEQ*DK_ + j)
                               : (Wv + (size_t)h*DSEQ*DV_ + (j - DK_));
  u16* dst = Wc + (size_t)h*WC_HSTRIDE + (size_t)j*32;
  for (int d = threadIdx.x; d < DSEQ; d += blockDim.x)
    dst[(size_t)(d >> 5)*WC_KSTRIDE + (d & 31)] = f2bf(src[(size_t)d*64]);
}

// S (fp32) -> Sb (bf16), flat; 8-elem granules, coalesced
__global__ void s2bf_kernel(const float* __restrict__ S, u16* __restrict__ Sb) {
  const size_t G = (size_t)B_*L_*DSEQ/8;
  for (size_t i = (size_t)blockIdx.x*256 + threadIdx.x; i < G; i += (size_t)4096*256) {
    const float4* sp = (const float4*)(S + i*8);
    float4 v0 = sp[0], v1 = sp[1];
    bf16x8 wv;
    wv[0]=(short)f2bf(v0.x); wv[1]=(short)f2bf(v0.y);
    wv[2]=(short)f2bf(v0.z); wv[3]=(short)f2bf(v0.w);
    wv[4]=(short)f2bf(v1.x); wv[5]=(short)f2bf(v1.y);
    wv[6]=(short)f2bf(v1.z); wv[7]=(short)f2bf(v1.w);
    *(bf16x8*)(Sb + i*8) = wv;
  }
}

// Q[b][h][k] = tanh(sum_d X[b,d]*Wq[h,d,k]); grid (H, B/4), block 64
__global__ void q_proj_kernel(const float* __restrict__ X,
                              const float* __restrict__ Wq,
                              float* __restrict__ Q) {
  const int h = blockIdx.x, b0 = blockIdx.y*4, k = threadIdx.x;
  const float* w = Wq + (size_t)h*DGLB*DK_ + k;
  float a0=0.f, a1=0.f, a2=0.f, a3=0.f;
  for (int d = 0; d < DGLB; ++d) {
    float wv = w[(size_t)d*DK_];
    a0 += X[(size_t)(b0+0)*DGLB + d]*wv;
    a1 += X[(size_t)(b0+1)*DGLB + d]*wv;
    a2 += X[(size_t)(b0+2)*DGLB + d]*wv;
    a3 += X[(size_t)(b0+3)*DGLB + d]*wv;
  }
  Q[((size_t)(b0+0)*H_+h)*DK_+k] = tanhf(a0);
  Q[((size_t)(b0+1)*H_+h)*DK_+k] = tanhf(a1);
  Q[((size_t)(b0+2)*H_+h)*DK_+k] = tanhf(a2);
  Q[((size_t)(b0+3)*H_+h)*DK_+k] = tanhf(a3);
}

// grid: 8192 blocks, 256 thr = 4 waves, 3 blocks/CU (r12 pipeline shape).
// BALANCED TILE: block = ONE head x 128 rows (M=128, N=128). Wave w:
// 128 rows x 32 cols (cols w*32..w*32+31: w<2 -> K-proj, w>=2 -> V-proj),
// acc[8][2] (64 regs, same as r12; B prefetch regs HALVE to 32).
// B L2 traffic halves (4->2 GiB): r12 was B-L2-BW-bound (58 B/cyc/CU
// demand vs ~56 available). A staging doubles (L3-resident Sb absorbs).
// head = id&15 (XCD id&7 gets heads x, x+8: 512 KB Wc L2-hot); tile
// diagonal-offset per head. 16 phases x (BK=64) via 3 x 16 KB LDS bufs,
// stage(s+2) issue-early, counted vmcnt(12)/(8). A rows 128 B, 8 x 16 B
// slots, XOR swizzle slot^(row&7) applied on gload_lds global source.
template<int BF16SRC>
__global__ __launch_bounds__(256, 3) void fused_kernel(
    const float* __restrict__ S, const u16* __restrict__ Sb,
    const u16* __restrict__ Wc, const float* __restrict__ Q,
    float* __restrict__ part) {
  __shared__ u16   Slds[3*8192];     // 3 x 16 KB, A rows 128 B
  __shared__ float lpart[2][128];    // logit partials from K-waves 0,1

  const int id   = blockIdx.x;
  const int head = id & 15;          // XCD id&7 serves heads x, x+8
  const int m    = id >> 4;          // 0..511
  const int tile = (m + (head << 5)) & 511;   // de-phase the 16 readers
  const int b    = tile >> 4, t2 = tile & 15; // 128-row tile within b

  const int tid  = threadIdx.x;
  const int wave = tid >> 6, lane = tid & 63;
  const int lhi  = lane >> 4, llo = lane & 15;
  const int llo7 = llo & 7;

  int arow[8];
  #pragma unroll
  for (int rt = 0; rt < 8; ++rt) arow[rt] = (rt*16 + llo)*128;  // bytes

  const u16*   Sv = Sb + ((size_t)b*L_ + (size_t)t2*128)*DSEQ;
  const float* Sf = S  + ((size_t)b*L_ + (size_t)t2*128)*DSEQ;

  // stage phase sub (128 rows x 64 k = 16 KB) into buf[sub%3]:
  // chunk j (1 KB) = rows 8j..8j+7; lane l -> row 8j+(l>>3), slot q=l&7,
  // logical granule g = q ^ (row&7) fetched from global (src swizzle);
  // LDS dest linear: chunk base + lane*16.
  auto stage_gl = [&](int sub) {
    const int bs = (sub % 3) * 8192;           // u16 offset (16 KB)
    const int ko = sub * 64;
    #pragma unroll
    for (int it = 0; it < 4; ++it) {
      const int j   = wave*4 + it;
      const int row = 8*j + (lane >> 3);
      const int g   = (lane & 7) ^ (row & 7);
      const u16* gp = Sv + (size_t)row*DSEQ + ko + (g << 3);
      __builtin_amdgcn_global_load_lds(
          (const AS1 void*)gp, (AS3 void*)(Slds + bs + j*512), 16, 0, 0);
    }
  };
  auto stage_reg = [&](int sub) {              // fp32 fallback
    const int bs = (sub % 3) * 16384;          // bytes
    const int ko = sub * 64;
    #pragma unroll
    for (int it = 0; it < 4; ++it) {
      int f = it*256 + tid, row = f >> 3, q = f & 7;
      int g = q ^ (row & 7);
      const float4* sp = (const float4*)(Sf + (size_t)row*DSEQ + ko + g*8);
      float4 v0 = sp[0], v1 = sp[1];
      bf16x8 wv;
      wv[0]=(short)f2bf(v0.x); wv[1]=(short)f2bf(v0.y);
      wv[2]=(short)f2bf(v0.z); wv[3]=(short)f2bf(v0.w);
      wv[4]=(short)f2bf(v1.x); wv[5]=(short)f2bf(v1.y);
      wv[6]=(short)f2bf(v1.z); wv[7]=(short)f2bf(v1.w);
      *(bf16x8*)((char*)Slds + bs + row*128 + q*16) = wv;
    }
  };

  f32x4 acc[8][2];
  #pragma unroll
  for (int rt = 0; rt < 8; ++rt) {
    acc[rt][0] = {0.f,0.f,0.f,0.f};
    acc[rt][1] = {0.f,0.f,0.f,0.f};
  }

  // B base: col j = wave*32 + c*16 + llo -> wb + c*512 (+ ks*WC_KSTRIDE)
  const u16* wb = Wc + (size_t)head*WC_HSTRIDE
                     + (size_t)(wave*32 + llo)*32 + lhi*8;
  if (BF16SRC) {
    stage_gl(0);
    stage_gl(1);
    __builtin_amdgcn_sched_barrier(0);
  }
  bf16x8 bA[2], bB[2], bC[2], bD[2];           // steps g..g+3, distance 4
  #pragma unroll
  for (int c = 0; c < 2; ++c) bA[c] = *(const bf16x8*)(wb + (size_t)0*WC_KSTRIDE + c*512);
  #pragma unroll
  for (int c = 0; c < 2; ++c) bB[c] = *(const bf16x8*)(wb + (size_t)1*WC_KSTRIDE + c*512);
  #pragma unroll
  for (int c = 0; c < 2; ++c) bC[c] = *(const bf16x8*)(wb + (size_t)2*WC_KSTRIDE + c*512);
  #pragma unroll
  for (int c = 0; c < 2; ++c) bD[c] = *(const bf16x8*)(wb + (size_t)3*WC_KSTRIDE + c*512);
  const u16* wbp = wb + (size_t)4*WC_KSTRIDE;  // rolling refill pointer
  if (BF16SRC) PHASE_BARRIER(12);   // stage(0) done; stage(1)+Binit in flight

  // one k-step: consume BUF (step s*2+kk), refill with step +4
#define KSTEP(BUF, kk)                                                        \
  do {                                                                        \
    const int colb = (((kk)*4 + lhi) ^ llo7) << 4;                            \
    __builtin_amdgcn_s_setprio(1);                                            \
    _Pragma("unroll")                                                         \
    for (int rt = 0; rt < 8; ++rt) {                                          \
      bf16x8 af = *(const bf16x8*)(cb + arow[rt] + colb);                     \
      acc[rt][0] = __builtin_amdgcn_mfma_f32_16x16x32_bf16(af, BUF[0], acc[rt][0], 0,0,0); \
      acc[rt][1] = __builtin_amdgcn_mfma_f32_16x16x32_bf16(af, BUF[1], acc[rt][1], 0,0,0); \
    }                                                                         \
    __builtin_amdgcn_s_setprio(0);                                            \
    BUF[0] = *(const bf16x8*)(wbp);                                           \
    BUF[1] = *(const bf16x8*)(wbp + 512);                                     \
    wbp += ((s*2 + (kk) + 4) == 31) ? -(ptrdiff_t)(31*WC_KSTRIDE)             \
                                    : (ptrdiff_t)WC_KSTRIDE;                  \
  } while (0)

  #pragma unroll
  for (int s = 0; s < 16; ++s) {
    if (BF16SRC) {
      if (s <= 13) { stage_gl(s + 2); __builtin_amdgcn_sched_barrier(0); }
    } else {
      stage_reg(s);
      __syncthreads();
    }
    const char* cb = (const char*)Slds + (s % 3)*16384;
    if (s & 1) { KSTEP(bC, 0); KSTEP(bD, 1); }
    else       { KSTEP(bA, 0); KSTEP(bB, 1); }
    if (BF16SRC) {
      // newest in flight: B_s(4) + stage(s+2)(4) + B_{s-1}(4) = 12
      if (s <= 13)      PHASE_BARRIER(12);
      else if (s == 14) PHASE_BARRIER(8);
      // s == 15: epilogue __syncthreads drains
    } else {
      __syncthreads();
    }
  }
#undef KSTEP

  // ---- epilogue: waves 0,1 = K-proj logit partials; 2,3 = V-proj ----
  if (wave < 2) {
    const float* Qb = Q + ((size_t)b*H_ + head)*DK_;
    float q0 = Qb[wave*32 + llo];
    float q1 = Qb[wave*32 + 16 + llo];
    #pragma unroll
    for (int rt = 0; rt < 8; ++rt) {
      #pragma unroll
      for (int r = 0; r < 4; ++r) {
        float pl = q0*tanh_fast(acc[rt][0][r]) + q1*tanh_fast(acc[rt][1][r]);
        pl += __shfl_xor(pl, 1); pl += __shfl_xor(pl, 2);
        pl += __shfl_xor(pl, 4); pl += __shfl_xor(pl, 8);
        if (llo == 0) lpart[wave][rt*16 + lhi*4 + r] = pl;
      }
    }
  } else {
    #pragma unroll
    for (int rt = 0; rt < 8; ++rt)
      #pragma unroll
      for (int c = 0; c < 2; ++c)
        #pragma unroll
        for (int r = 0; r < 4; ++r) {
          float x = acc[rt][c][r];
          acc[rt][c][r] = 0.5f*x*(1.f + erf_fast(x*0.70710678118654752f));
        }
  }
  __syncthreads();

  if (wave >= 2) {
    #pragma unroll
    for (int g = 0; g < 2; ++g) {    // two 64-row groups
      float lg = (lpart[0][g*64 + lane] + lpart[1][g*64 + lane]) * 0.125f;
      float mx = lg;
      #pragma unroll
      for (int mk = 1; mk < 64; mk <<= 1) mx = fmaxf(mx, __shfl_xor(mx, mk));
      float ev = __expf(lg - mx);
      float sv = ev;
      #pragma unroll
      for (int mk = 1; mk < 64; mk <<= 1) sv += __shfl_xor(sv, mk);

      float er[16];
      #pragma unroll
      for (int rt4 = 0; rt4 < 4; ++rt4)
        #pragma unroll
        for (int r = 0; r < 4; ++r)
          er[rt4*4 + r] = __shfl(ev, rt4*16 + lhi*4 + r);

      float* pt = part + (((size_t)b*H_ + head)*NT + t2*2 + g)*PSTRIDE;
      #pragma unroll
      for (int c = 0; c < 2; ++c) {
        float y = 0.f;
        #pragma unroll
        for (int rt4 = 0; rt4 < 4; ++rt4)
          #pragma unroll
          for (int r = 0; r < 4; ++r)
            y += er[rt4*4 + r]*acc[g*4 + rt4][c][r];
        y += __shfl_xor(y, 16); y += __shfl_xor(y, 32);
        if (lhi == 0) pt[2 + (wave - 2)*32 + c*16 + llo] = y;
      }
      if (wave == 2 && lane == 0) { pt[0] = mx; pt[1] = sv; }
    }
  }
}

// merge NT tile-partials per (b,h); grid (H, B), block 64
__global__ void finalize_kernel(const float* __restrict__ part,
                                float* __restrict__ out) {
  const int h = blockIdx.x, b = blockIdx.y, v = threadIdx.x;
  const float* p = part + ((size_t)b*H_ + h)*(size_t)NT*PSTRIDE;
  float M = -3.0e38f;
  for (int tt = 0; tt < NT; ++tt) M = fmaxf(M, p[tt*PSTRIDE]);
  float ss = 0.f, y = 0.f;
  for (int tt = 0; tt < NT; ++tt) {
    float w = expf(p[tt*PSTRIDE] - M);
    ss += w*p[tt*PSTRIDE + 1];
    y  += w*p[tt*PSTRIDE + 2 + v];
  }
  out[((size_t)b*H_ + h)*DV_ + v] = y/ss;
}

extern "C" void kernel_launch(void* const* d_in, const int* in_sizes, int n_in,
                              void* d_out, int out_size, void* d_ws, size_t ws_size,
                              hipStream_t stream) {
  const float* X  = (const float*)d_in[0];
  const float* S  = (const float*)d_in[1];
  const float* Wq = (const float*)d_in[2];
  const float* Wk = (const float*)d_in[3];
  const float* Wv = (const float*)d_in[4];
  float* out = (float*)d_out;

  char* ws = (char*)d_ws;
  u16*   Wc    = (u16*)ws;                              // 4 MiB
  float* Qbuf  = (float*)(ws + (4u<<20));               // 128 KiB
  float* part  = (float*)(ws + (4u<<20) + (128u<<10));  // ~4.3 MiB
  u16*   Sb    = (u16*)(ws + (16u<<20));                // 128 MiB (optional)
  const bool useBf = ws_size >= (144ull << 20);

  pack_w_kernel  <<<dim3(H_, 128),  256, 0, stream>>>(Wk, Wv, Wc);
  q_proj_kernel  <<<dim3(H_, B_/4),  64, 0, stream>>>(X, Wq, Qbuf);
  if (useBf) {
    s2bf_kernel       <<<dim3(4096), 256, 0, stream>>>(S, Sb);
    fused_kernel<1>   <<<dim3(8192), 256, 0, stream>>>(S, Sb, Wc, Qbuf, part);
  } else {
    fused_kernel<0>   <<<dim3(8192), 256, 0, stream>>>(S, Sb, Wc, Qbuf, part);
  }
  finalize_kernel<<<dim3(H_, B_),    64, 0, stream>>>(part, out);
}

// Round 17
// 435.336 us; speedup vs baseline: 1.5099x; 1.1408x over previous
//
#include <hip/hip_runtime.h>
#include <math.h>

#define B_   32
#define L_   2048
#define DSEQ 1024
#define DGLB 1024
#define H_   16
#define DK_  64
#define DV_  64
#define NT   32           // 64-row groups per (b,h)
#define PSTRIDE 66        // m, s, y[64]

// Wc2 layout: [h][ks(32)][j(128)][e(32)] bf16; d = ks*32 + e
#define WC_KSTRIDE 4096            // 128*32 elems per k-step
#define WC_HSTRIDE 131072          // 32*4096 elems per head

#define AS1 __attribute__((address_space(1)))
#define AS3 __attribute__((address_space(3)))

using u16    = unsigned short;
using bf16x8 = __attribute__((ext_vector_type(8))) short;
using f32x4  = __attribute__((ext_vector_type(4))) float;

__device__ __forceinline__ u16 f2bf(float x) {
  union { float f; unsigned int u; } v; v.f = x;
  return (u16)((v.u + 0x7fffu + ((v.u >> 16) & 1u)) >> 16);   // RNE
}

__device__ __forceinline__ float tanh_fast(float x) {
  float e = __builtin_exp2f(x * 2.885390081777927f);   // 2*log2(e)
  return 1.f - 2.f/(e + 1.f);
}

__device__ __forceinline__ float erf_fast(float x) {
  float ax = fabsf(x);
  float t  = 1.f/(1.f + 0.3275911f*ax);
  float p  = t*(0.254829592f + t*(-0.284496736f + t*(1.421413741f +
             t*(-1.453152027f + t*1.061405429f))));
  float e  = __builtin_exp2f(-ax*ax*1.4426950408889634f);  // e^{-x^2}
  float r  = 1.f - p*e;
  return copysignf(r, x);
}

#define PHASE_BARRIER(N)                                   \
  do {                                                     \
    __builtin_amdgcn_sched_barrier(0);                     \
    asm volatile("s_waitcnt vmcnt(" #N ")" ::: "memory");  \
    __builtin_amdgcn_s_barrier();                          \
    __builtin_amdgcn_sched_barrier(0);                     \
  } while (0)

// Wc2[h][d>>5][j][d&31]: j<64 -> Wk[h,:,j], else Wv[h,:,j-64]
__global__ void pack_w_kernel(const float* __restrict__ Wk,
                              const float* __restrict__ Wv,
                              u16* __restrict__ Wc) {
  const int h = blockIdx.x, j = blockIdx.y;
  const float* src = (j < DK_) ? (Wk + (size_t)h*DSEQ*DK_ + j)
                               : (Wv + (size_t)h*DSEQ*DV_ + (j - DK_));
  u16* dst = Wc + (size_t)h*WC_HSTRIDE + (size_t)j*32;
  for (int d = threadIdx.x; d < DSEQ; d += blockDim.x)
    dst[(size_t)(d >> 5)*WC_KSTRIDE + (d & 31)] = f2bf(src[(size_t)d*64]);
}

// S (fp32) -> Sb (bf16), flat; 8-elem granules, coalesced
__global__ void s2bf_kernel(const float* __restrict__ S, u16* __restrict__ Sb) {
  const size_t G = (size_t)B_*L_*DSEQ/8;
  for (size_t i = (size_t)blockIdx.x*256 + threadIdx.x; i < G; i += (size_t)4096*256) {
    const float4* sp = (const float4*)(S + i*8);
    float4 v0 = sp[0], v1 = sp[1];
    bf16x8 wv;
    wv[0]=(short)f2bf(v0.x); wv[1]=(short)f2bf(v0.y);
    wv[2]=(short)f2bf(v0.z); wv[3]=(short)f2bf(v0.w);
    wv[4]=(short)f2bf(v1.x); wv[5]=(short)f2bf(v1.y);
    wv[6]=(short)f2bf(v1.z); wv[7]=(short)f2bf(v1.w);
    *(bf16x8*)(Sb + i*8) = wv;
  }
}

// Q[b][h][k] = tanh(sum_d X[b,d]*Wq[h,d,k]); grid (H, B/4), 256 thr.
// COALESCED: threads (dd=tid>>6, k=tid&63); Wq row reads are k-contiguous
// (256 B/wave); X element broadcast. LDS reduce over the 4 dd-groups.
// (old version read Wq at 256 B stride per thread -> 16x overfetch.)
__global__ void q_proj_kernel(const float* __restrict__ X,
                              const float* __restrict__ Wq,
                              float* __restrict__ Q) {
  __shared__ float red[4][4][64];   // [dd][bb][k]
  const int h = blockIdx.x, b0 = blockIdx.y*4;
  const int k = threadIdx.x & 63, dd = threadIdx.x >> 6;
  const float* w = Wq + (size_t)h*DGLB*DK_ + (size_t)dd*256*DK_ + k;
  float a0=0.f, a1=0.f, a2=0.f, a3=0.f;
  for (int d = 0; d < 256; ++d) {
    float wv = w[(size_t)d*DK_];
    a0 += X[(size_t)(b0+0)*DGLB + dd*256 + d]*wv;
    a1 += X[(size_t)(b0+1)*DGLB + dd*256 + d]*wv;
    a2 += X[(size_t)(b0+2)*DGLB + dd*256 + d]*wv;
    a3 += X[(size_t)(b0+3)*DGLB + dd*256 + d]*wv;
  }
  red[dd][0][k]=a0; red[dd][1][k]=a1; red[dd][2][k]=a2; red[dd][3][k]=a3;
  __syncthreads();
  if (dd == 0) {
    #pragma unroll
    for (int bb = 0; bb < 4; ++bb) {
      float s = red[0][bb][k]+red[1][bb][k]+red[2][bb][k]+red[3][bb][k];
      Q[((size_t)(b0+bb)*H_+h)*DK_+k] = tanhf(s);
    }
  }
}

// grid: 8192 blocks, 256 thr = 4 waves, 3 blocks/CU.
// Balanced tile (r16): block = ONE head x 128 rows (M=128, N=128); wave w
// = 128 rows x 32 cols (w<2 K-proj, w>=2 V-proj), acc[8][2].
// A-DUP FIX: xcd = id&7 serves heads xcd, xcd+8. idx = id>>3:
// head = xcd + 8*(idx&1), mm = idx>>1, tile = (mm + xcd*64) & 511.
// The TWO same-XCD readers of a tile are ADJACENT blocks -> their A
// fetches merge in the shared per-XCD L2 (one HBM fill serves both);
// cross-XCD readers are 1024 ids apart (> ~768 resident) -> sequential,
// served by L3 (Sb=128 MB fits). Kills r16's 16x concurrent-miss dup.
// 16 phases x BK=64 via 3 x 16 KB LDS bufs, stage(s+2) issue-early,
// counted vmcnt(12)/(8). A rows 128 B, 8 x 16 B slots, XOR swizzle
// slot^(row&7) applied on gload_lds global source.
template<int BF16SRC>
__global__ __launch_bounds__(256, 3) void fused_kernel(
    const float* __restrict__ S, const u16* __restrict__ Sb,
    const u16* __restrict__ Wc, const float* __restrict__ Q,
    float* __restrict__ part) {
  __shared__ u16   Slds[3*8192];     // 3 x 16 KB, A rows 128 B
  __shared__ float lpart[2][128];    // logit partials from K-waves 0,1

  const int id   = blockIdx.x;
  const int xcd  = id & 7;
  const int idx  = id >> 3;
  const int head = xcd + 8*(idx & 1);
  const int mm   = idx >> 1;                  // 0..511
  const int tile = (mm + (xcd << 6)) & 511;
  const int b    = tile >> 4, t2 = tile & 15; // 128-row tile within b

  const int tid  = threadIdx.x;
  const int wave = tid >> 6, lane = tid & 63;
  const int lhi  = lane >> 4, llo = lane & 15;
  const int llo7 = llo & 7;

  int arow[8];
  #pragma unroll
  for (int rt = 0; rt < 8; ++rt) arow[rt] = (rt*16 + llo)*128;  // bytes

  const u16*   Sv = Sb + ((size_t)b*L_ + (size_t)t2*128)*DSEQ;
  const float* Sf = S  + ((size_t)b*L_ + (size_t)t2*128)*DSEQ;

  // stage phase sub (128 rows x 64 k = 16 KB) into buf[sub%3]:
  // chunk j (1 KB) = rows 8j..8j+7; lane l -> row 8j+(l>>3), slot q=l&7,
  // logical granule g = q ^ (row&7) fetched from global (src swizzle).
  auto stage_gl = [&](int sub) {
    const int bs = (sub % 3) * 8192;           // u16 offset (16 KB)
    const int ko = sub * 64;
    #pragma unroll
    for (int it = 0; it < 4; ++it) {
      const int j   = wave*4 + it;
      const int row = 8*j + (lane >> 3);
      const int g   = (lane & 7) ^ (row & 7);
      const u16* gp = Sv + (size_t)row*DSEQ + ko + (g << 3);
      __builtin_amdgcn_global_load_lds(
          (const AS1 void*)gp, (AS3 void*)(Slds + bs + j*512), 16, 0, 0);
    }
  };
  auto stage_reg = [&](int sub) {              // fp32 fallback
    const int bs = (sub % 3) * 16384;          // bytes
    const int ko = sub * 64;
    #pragma unroll
    for (int it = 0; it < 4; ++it) {
      int f = it*256 + tid, row = f >> 3, q = f & 7;
      int g = q ^ (row & 7);
      const float4* sp = (const float4*)(Sf + (size_t)row*DSEQ + ko + g*8);
      float4 v0 = sp[0], v1 = sp[1];
      bf16x8 wv;
      wv[0]=(short)f2bf(v0.x); wv[1]=(short)f2bf(v0.y);
      wv[2]=(short)f2bf(v0.z); wv[3]=(short)f2bf(v0.w);
      wv[4]=(short)f2bf(v1.x); wv[5]=(short)f2bf(v1.y);
      wv[6]=(short)f2bf(v1.z); wv[7]=(short)f2bf(v1.w);
      *(bf16x8*)((char*)Slds + bs + row*128 + q*16) = wv;
    }
  };

  f32x4 acc[8][2];
  #pragma unroll
  for (int rt = 0; rt < 8; ++rt) {
    acc[rt][0] = {0.f,0.f,0.f,0.f};
    acc[rt][1] = {0.f,0.f,0.f,0.f};
  }

  // B base: col j = wave*32 + c*16 + llo -> wb + c*512 (+ ks*WC_KSTRIDE)
  const u16* wb = Wc + (size_t)head*WC_HSTRIDE
                     + (size_t)(wave*32 + llo)*32 + lhi*8;
  if (BF16SRC) {
    stage_gl(0);
    stage_gl(1);
    __builtin_amdgcn_sched_barrier(0);
  }
  bf16x8 bA[2], bB[2], bC[2], bD[2];           // steps g..g+3, distance 4
  #pragma unroll
  for (int c = 0; c < 2; ++c) bA[c] = *(const bf16x8*)(wb + (size_t)0*WC_KSTRIDE + c*512);
  #pragma unroll
  for (int c = 0; c < 2; ++c) bB[c] = *(const bf16x8*)(wb + (size_t)1*WC_KSTRIDE + c*512);
  #pragma unroll
  for (int c = 0; c < 2; ++c) bC[c] = *(const bf16x8*)(wb + (size_t)2*WC_KSTRIDE + c*512);
  #pragma unroll
  for (int c = 0; c < 2; ++c) bD[c] = *(const bf16x8*)(wb + (size_t)3*WC_KSTRIDE + c*512);
  const u16* wbp = wb + (size_t)4*WC_KSTRIDE;  // rolling refill pointer
  if (BF16SRC) PHASE_BARRIER(12);   // stage(0) done; stage(1)+Binit in flight

  // one k-step: consume BUF (step s*2+kk), refill with step +4
#define KSTEP(BUF, kk)                                                        \
  do {                                                                        \
    const int colb = (((kk)*4 + lhi) ^ llo7) << 4;                            \
    __builtin_amdgcn_s_setprio(1);                                            \
    _Pragma("unroll")                                                         \
    for (int rt = 0; rt < 8; ++rt) {                                          \
      bf16x8 af = *(const bf16x8*)(cb + arow[rt] + colb);                     \
      acc[rt][0] = __builtin_amdgcn_mfma_f32_16x16x32_bf16(af, BUF[0], acc[rt][0], 0,0,0); \
      acc[rt][1] = __builtin_amdgcn_mfma_f32_16x16x32_bf16(af, BUF[1], acc[rt][1], 0,0,0); \
    }                                                                         \
    __builtin_amdgcn_s_setprio(0);                                            \
    BUF[0] = *(const bf16x8*)(wbp);                                           \
    BUF[1] = *(const bf16x8*)(wbp + 512);                                     \
    wbp += ((s*2 + (kk) + 4) == 31) ? -(ptrdiff_t)(31*WC_KSTRIDE)             \
                                    : (ptrdiff_t)WC_KSTRIDE;                  \
  } while (0)

  #pragma unroll
  for (int s = 0; s < 16; ++s) {
    if (BF16SRC) {
      if (s <= 13) { stage_gl(s + 2); __builtin_amdgcn_sched_barrier(0); }
    } else {
      stage_reg(s);
      __syncthreads();
    }
    const char* cb = (const char*)Slds + (s % 3)*16384;
    if (s & 1) { KSTEP(bC, 0); KSTEP(bD, 1); }
    else       { KSTEP(bA, 0); KSTEP(bB, 1); }
    if (BF16SRC) {
      // newest in flight: B_s(4) + stage(s+2)(4) + B_{s-1}(4) = 12
      if (s <= 13)      PHASE_BARRIER(12);
      else if (s == 14) PHASE_BARRIER(8);
      // s == 15: epilogue __syncthreads drains
    } else {
      __syncthreads();
    }
  }
#undef KSTEP

  // ---- epilogue: waves 0,1 = K-proj logit partials; 2,3 = V-proj ----
  if (wave < 2) {
    const float* Qb = Q + ((size_t)b*H_ + head)*DK_;
    float q0 = Qb[wave*32 + llo];
    float q1 = Qb[wave*32 + 16 + llo];
    #pragma unroll
    for (int rt = 0; rt < 8; ++rt) {
      #pragma unroll
      for (int r = 0; r < 4; ++r) {
        float pl = q0*tanh_fast(acc[rt][0][r]) + q1*tanh_fast(acc[rt][1][r]);
        pl += __shfl_xor(pl, 1); pl += __shfl_xor(pl, 2);
        pl += __shfl_xor(pl, 4); pl += __shfl_xor(pl, 8);
        if (llo == 0) lpart[wave][rt*16 + lhi*4 + r] = pl;
      }
    }
  } else {
    #pragma unroll
    for (int rt = 0; rt < 8; ++rt)
      #pragma unroll
      for (int c = 0; c < 2; ++c)
        #pragma unroll
        for (int r = 0; r < 4; ++r) {
          float x = acc[rt][c][r];
          acc[rt][c][r] = 0.5f*x*(1.f + erf_fast(x*0.70710678118654752f));
        }
  }
  __syncthreads();

  if (wave >= 2) {
    #pragma unroll
    for (int g = 0; g < 2; ++g) {    // two 64-row groups
      float lg = (lpart[0][g*64 + lane] + lpart[1][g*64 + lane]) * 0.125f;
      float mx = lg;
      #pragma unroll
      for (int mk = 1; mk < 64; mk <<= 1) mx = fmaxf(mx, __shfl_xor(mx, mk));
      float ev = __expf(lg - mx);
      float sv = ev;
      #pragma unroll
      for (int mk = 1; mk < 64; mk <<= 1) sv += __shfl_xor(sv, mk);

      float er[16];
      #pragma unroll
      for (int rt4 = 0; rt4 < 4; ++rt4)
        #pragma unroll
        for (int r = 0; r < 4; ++r)
          er[rt4*4 + r] = __shfl(ev, rt4*16 + lhi*4 + r);

      float* pt = part + (((size_t)b*H_ + head)*NT + t2*2 + g)*PSTRIDE;
      #pragma unroll
      for (int c = 0; c < 2; ++c) {
        float y = 0.f;
        #pragma unroll
        for (int rt4 = 0; rt4 < 4; ++rt4)
          #pragma unroll
          for (int r = 0; r < 4; ++r)
            y += er[rt4*4 + r]*acc[g*4 + rt4][c][r];
        y += __shfl_xor(y, 16); y += __shfl_xor(y, 32);
        if (lhi == 0) pt[2 + (wave - 2)*32 + c*16 + llo] = y;
      }
      if (wave == 2 && lane == 0) { pt[0] = mx; pt[1] = sv; }
    }
  }
}

// merge NT tile-partials per (b,h); grid (H, B), block 64
__global__ void finalize_kernel(const float* __restrict__ part,
                                float* __restrict__ out) {
  const int h = blockIdx.x, b = blockIdx.y, v = threadIdx.x;
  const float* p = part + ((size_t)b*H_ + h)*(size_t)NT*PSTRIDE;
  float M = -3.0e38f;
  for (int tt = 0; tt < NT; ++tt) M = fmaxf(M, p[tt*PSTRIDE]);
  float ss = 0.f, y = 0.f;
  for (int tt = 0; tt < NT; ++tt) {
    float w = expf(p[tt*PSTRIDE] - M);
    ss += w*p[tt*PSTRIDE + 1];
    y  += w*p[tt*PSTRIDE + 2 + v];
  }
  out[((size_t)b*H_ + h)*DV_ + v] = y/ss;
}

extern "C" void kernel_launch(void* const* d_in, const int* in_sizes, int n_in,
                              void* d_out, int out_size, void* d_ws, size_t ws_size,
                              hipStream_t stream) {
  const float* X  = (const float*)d_in[0];
  const float* S  = (const float*)d_in[1];
  const float* Wq = (const float*)d_in[2];
  const float* Wk = (const float*)d_in[3];
  const float* Wv = (const float*)d_in[4];
  float* out = (float*)d_out;

  char* ws = (char*)d_ws;
  u16*   Wc    = (u16*)ws;                              // 4 MiB
  float* Qbuf  = (float*)(ws + (4u<<20));               // 128 KiB
  float* part  = (float*)(ws + (4u<<20) + (128u<<10));  // ~4.3 MiB
  u16*   Sb    = (u16*)(ws + (16u<<20));                // 128 MiB (optional)
  const bool useBf = ws_size >= (144ull << 20);

  pack_w_kernel  <<<dim3(H_, 128),  256, 0, stream>>>(Wk, Wv, Wc);
  q_proj_kernel  <<<dim3(H_, B_/4), 256, 0, stream>>>(X, Wq, Qbuf);
  if (useBf) {
    s2bf_kernel       <<<dim3(4096), 256, 0, stream>>>(S, Sb);
    fused_kernel<1>   <<<dim3(8192), 256, 0, stream>>>(S, Sb, Wc, Qbuf, part);
  } else {
    fused_kernel<0>   <<<dim3(8192), 256, 0, stream>>>(S, Sb, Wc, Qbuf, part);
  }
  finalize_kernel<<<dim3(H_, B_),    64, 0, stream>>>(part, out);
}

// Round 18
// 418.437 us; speedup vs baseline: 1.5709x; 1.0404x over previous
//
#include <hip/hip_runtime.h>
#include <math.h>

#define B_   32
#define L_   2048
#define DSEQ 1024
#define DGLB 1024
#define H_   16
#define DK_  64
#define DV_  64
#define LT   64
#define NT   (L_/LT)      // 32
#define PSTRIDE 66        // m, s, y[64]

// Wc2 layout: [h][ks(32)][j(128)][e(32)] bf16; d = ks*32 + e
#define WC_KSTRIDE 4096            // 128*32 elems per k-step
#define WC_HSTRIDE 131072          // 32*4096 elems per head

#define AS1 __attribute__((address_space(1)))
#define AS3 __attribute__((address_space(3)))

using u16    = unsigned short;
using bf16x8 = __attribute__((ext_vector_type(8))) short;
using f32x4  = __attribute__((ext_vector_type(4))) float;

__device__ __forceinline__ u16 f2bf(float x) {
  union { float f; unsigned int u; } v; v.f = x;
  return (u16)((v.u + 0x7fffu + ((v.u >> 16) & 1u)) >> 16);   // RNE
}

__device__ __forceinline__ float tanh_fast(float x) {
  float e = __builtin_exp2f(x * 2.885390081777927f);   // 2*log2(e)
  return 1.f - 2.f/(e + 1.f);
}

__device__ __forceinline__ float erf_fast(float x) {
  float ax = fabsf(x);
  float t  = 1.f/(1.f + 0.3275911f*ax);
  float p  = t*(0.254829592f + t*(-0.284496736f + t*(1.421413741f +
             t*(-1.453152027f + t*1.061405429f))));
  float e  = __builtin_exp2f(-ax*ax*1.4426950408889634f);  // e^{-x^2}
  float r  = 1.f - p*e;
  return copysignf(r, x);
}

#define PHASE_BARRIER(N)                                   \
  do {                                                     \
    __builtin_amdgcn_sched_barrier(0);                     \
    asm volatile("s_waitcnt vmcnt(" #N ")" ::: "memory");  \
    __builtin_amdgcn_s_barrier();                          \
    __builtin_amdgcn_sched_barrier(0);                     \
  } while (0)

// Wc2[h][d>>5][j][d&31]: j<64 -> Wk[h,:,j], else Wv[h,:,j-64]
__global__ void pack_w_kernel(const float* __restrict__ Wk,
                              const float* __restrict__ Wv,
                              u16* __restrict__ Wc) {
  const int h = blockIdx.x, j = blockIdx.y;
  const float* src = (j < DK_) ? (Wk + (size_t)h*DSEQ*DK_ + j)
                               : (Wv + (size_t)h*DSEQ*DV_ + (j - DK_));
  u16* dst = Wc + (size_t)h*WC_HSTRIDE + (size_t)j*32;
  for (int d = threadIdx.x; d < DSEQ; d += blockDim.x)
    dst[(size_t)(d >> 5)*WC_KSTRIDE + (d & 31)] = f2bf(src[(size_t)d*64]);
}

// S (fp32) -> Sb (bf16), flat; 8-elem granules, coalesced
__global__ void s2bf_kernel(const float* __restrict__ S, u16* __restrict__ Sb) {
  const size_t G = (size_t)B_*L_*DSEQ/8;
  for (size_t i = (size_t)blockIdx.x*256 + threadIdx.x; i < G; i += (size_t)4096*256) {
    const float4* sp = (const float4*)(S + i*8);
    float4 v0 = sp[0], v1 = sp[1];
    bf16x8 wv;
    wv[0]=(short)f2bf(v0.x); wv[1]=(short)f2bf(v0.y);
    wv[2]=(short)f2bf(v0.z); wv[3]=(short)f2bf(v0.w);
    wv[4]=(short)f2bf(v1.x); wv[5]=(short)f2bf(v1.y);
    wv[6]=(short)f2bf(v1.z); wv[7]=(short)f2bf(v1.w);
    *(bf16x8*)(Sb + i*8) = wv;
  }
}

// Q[b][h][k] = tanh(sum_d X[b,d]*Wq[h,d,k]); grid (H, B/4), 256 thr.
// Coalesced (r17): threads (dd=tid>>6, k=tid&63); Wq reads k-contiguous;
// LDS reduce over the 4 dd-groups.
__global__ void q_proj_kernel(const float* __restrict__ X,
                              const float* __restrict__ Wq,
                              float* __restrict__ Q) {
  __shared__ float red[4][4][64];   // [dd][bb][k]
  const int h = blockIdx.x, b0 = blockIdx.y*4;
  const int k = threadIdx.x & 63, dd = threadIdx.x >> 6;
  const float* w = Wq + (size_t)h*DGLB*DK_ + (size_t)dd*256*DK_ + k;
  float a0=0.f, a1=0.f, a2=0.f, a3=0.f;
  for (int d = 0; d < 256; ++d) {
    float wv = w[(size_t)d*DK_];
    a0 += X[(size_t)(b0+0)*DGLB + dd*256 + d]*wv;
    a1 += X[(size_t)(b0+1)*DGLB + dd*256 + d]*wv;
    a2 += X[(size_t)(b0+2)*DGLB + dd*256 + d]*wv;
    a3 += X[(size_t)(b0+3)*DGLB + dd*256 + d]*wv;
  }
  red[dd][0][k]=a0; red[dd][1][k]=a1; red[dd][2][k]=a2; red[dd][3][k]=a3;
  __syncthreads();
  if (dd == 0) {
    #pragma unroll
    for (int bb = 0; bb < 4; ++bb) {
      float s = red[0][bb][k]+red[1][bb][k]+red[2][bb][k]+red[3][bb][k];
      Q[((size_t)(b0+bb)*H_+h)*DK_+k] = tanhf(s);
    }
  }
}

// grid: 8192 linear blocks, 256 threads = 4 waves, 3 blocks/CU.
// r12 pipeline (verified 352 us) + r17's PAIRING retrofit:
//   xcd = id&7; j = xcd>>1 -> head-GROUP (pairs 2j,2j+1 = heads 4j..4j+3,
//   Wc slice 1 MB, L2-safe per r6); c = xcd&1 -> tile parity.
//   idx = id>>3: psel = idx&1 -> pair = 2j+psel; mm = idx>>1;
//   tile = ((mm + j*128)&511)*2 + c.
// Coverage: tile T (parity c) done by XCDs {c,c+2,c+4,c+6} x 2 psel =
// all 8 pairs exactly once. Adjacent same-XCD blocks (idx=2mm,2mm+1)
// stage the SAME A tile 8 ids apart -> L2-merged fetch (r17-verified
// mechanism); cross-XCD readers drop 8 -> 4.
// Pipeline: 8 sub-tiles of 128k via 3 x 16 KB LDS bufs, stage(s+2)
// issue-early, counted PHASE_BARRIER (prefetch never drained), B rolling
// pointer distance-4 (bA..bD), setprio around MFMA. Wave = (hp, K|V),
// tile 64 rows x 64 cols, acc[4][4].
template<int BF16SRC>
__global__ __launch_bounds__(256, 3) void fused_kernel(
    const float* __restrict__ S, const u16* __restrict__ Sb,
    const u16* __restrict__ Wc, const float* __restrict__ Q,
    float* __restrict__ part) {
  __shared__ u16   Slds[3*64*128];   // 3 x 16 KB, rows 256 B
  __shared__ float lpart[2][64];

  const int id   = blockIdx.x;
  const int xcd  = id & 7;
  const int j    = xcd >> 1;         // head-group 0..3 (pairs 2j, 2j+1)
  const int c    = xcd & 1;          // tile parity
  const int idx  = id >> 3;          // 0..1023
  const int psel = idx & 1;
  const int mm   = idx >> 1;         // 0..511
  const int pair = 2*j + psel;       // 0..7
  const int tile = (((mm + (j << 7)) & 511) << 1) | c;   // 0..1023
  const int t    = tile & (NT-1), b = tile >> 5;

  const int tid  = threadIdx.x;
  const int wave = tid >> 6, lane = tid & 63;
  const int lhi  = lane >> 4, llo = lane & 15;
  const int isV  = wave & 1,  hp  = wave >> 1;
  const int h    = pair*2 + hp;

  const u16* wb = Wc + (size_t)h*WC_HSTRIDE + (size_t)(isV*64 + llo)*32 + lhi*8;
  int arow[4];
  #pragma unroll
  for (int rt = 0; rt < 4; ++rt) arow[rt] = (rt*16 + llo)*256;  // bytes

  const u16*   Sv = Sb + ((size_t)b*L_ + (size_t)t*LT)*DSEQ;
  const float* Sf = S  + ((size_t)b*L_ + (size_t)t*LT)*DSEQ;

  // stage sub-tile (sub: 64 rows x 128 k = 16 KB) into buf[sub%3]
  auto stage_gl = [&](int sub) {
    const int bs = (sub % 3) * 8192;           // u16 offset (16 KB)
    const int ko = (sub & 7) * 128;
    #pragma unroll
    for (int it = 0; it < 4; ++it) {
      const int jj  = wave*4 + it;
      const int row = 4*jj + (lane >> 4);
      const int g   = (lane & 15) ^ (row & 15);
      const u16* gp = Sv + (size_t)row*DSEQ + ko + (g << 3);
      __builtin_amdgcn_global_load_lds(
          (const AS1 void*)gp, (AS3 void*)(Slds + bs + jj*512), 16, 0, 0);
    }
  };
  auto stage_reg = [&](int sub) {              // fp32 fallback
    const int bs = (sub % 3) * 16384;          // bytes
    const int ko = (sub & 7) * 128;
    #pragma unroll
    for (int it = 0; it < 4; ++it) {
      int f = it*256 + tid, row = f >> 4, q = f & 15;
      int g = q ^ (row & 15);
      const float4* sp = (const float4*)(Sf + (size_t)row*DSEQ + ko + g*8);
      float4 v0 = sp[0], v1 = sp[1];
      bf16x8 wv;
      wv[0]=(short)f2bf(v0.x); wv[1]=(short)f2bf(v0.y);
      wv[2]=(short)f2bf(v0.z); wv[3]=(short)f2bf(v0.w);
      wv[4]=(short)f2bf(v1.x); wv[5]=(short)f2bf(v1.y);
      wv[6]=(short)f2bf(v1.z); wv[7]=(short)f2bf(v1.w);
      *(bf16x8*)((char*)Slds + bs + row*256 + q*16) = wv;
    }
  };

  f32x4 acc[4][4];
  #pragma unroll
  for (int rt = 0; rt < 4; ++rt)
    #pragma unroll
    for (int cc = 0; cc < 4; ++cc) acc[rt][cc] = {0.f,0.f,0.f,0.f};

  // prologue: stage subs 0,1 (pinned first), then B init (steps 0..3)
  if (BF16SRC) {
    stage_gl(0);
    stage_gl(1);
    __builtin_amdgcn_sched_barrier(0);   // staging precedes B init in issue
  }
  bf16x8 bA[4], bB[4], bC[4], bD[4];
  #pragma unroll
  for (int cc = 0; cc < 4; ++cc) bA[cc] = *(const bf16x8*)(wb + (size_t)0*WC_KSTRIDE + cc*512);
  #pragma unroll
  for (int cc = 0; cc < 4; ++cc) bB[cc] = *(const bf16x8*)(wb + (size_t)1*WC_KSTRIDE + cc*512);
  #pragma unroll
  for (int cc = 0; cc < 4; ++cc) bC[cc] = *(const bf16x8*)(wb + (size_t)2*WC_KSTRIDE + cc*512);
  #pragma unroll
  for (int cc = 0; cc < 4; ++cc) bD[cc] = *(const bf16x8*)(wb + (size_t)3*WC_KSTRIDE + cc*512);
  const u16* wbp = wb + (size_t)4*WC_KSTRIDE;  // rolling refill pointer
  if (BF16SRC) PHASE_BARRIER(20);              // stage(0) done; rest in flight

  // one k-step (32 elems): consume BUF (step s*4+kk), refill with step +4
#define KSTEP(BUF, kk)                                                        \
  do {                                                                        \
    const int colb = (((kk)*4 + lhi) ^ llo) << 4;                             \
    __builtin_amdgcn_s_setprio(1);                                            \
    _Pragma("unroll")                                                         \
    for (int rt = 0; rt < 4; ++rt) {                                          \
      bf16x8 af = *(const bf16x8*)(cb + arow[rt] + colb);                     \
      acc[rt][0] = __builtin_amdgcn_mfma_f32_16x16x32_bf16(af, BUF[0], acc[rt][0], 0,0,0); \
      acc[rt][1] = __builtin_amdgcn_mfma_f32_16x16x32_bf16(af, BUF[1], acc[rt][1], 0,0,0); \
      acc[rt][2] = __builtin_amdgcn_mfma_f32_16x16x32_bf16(af, BUF[2], acc[rt][2], 0,0,0); \
      acc[rt][3] = __builtin_amdgcn_mfma_f32_16x16x32_bf16(af, BUF[3], acc[rt][3], 0,0,0); \
    }                                                                         \
    __builtin_amdgcn_s_setprio(0);                                            \
    {                                                                         \
      _Pragma("unroll")                                                       \
      for (int cc = 0; cc < 4; ++cc)                                          \
        BUF[cc] = *(const bf16x8*)(wbp + cc*512);                             \
      wbp += ((s*4 + (kk) + 4) == 31) ? -(ptrdiff_t)(31*WC_KSTRIDE)           \
                                      : (ptrdiff_t)WC_KSTRIDE;                \
    }                                                                         \
  } while (0)

  #pragma unroll
  for (int s = 0; s < 8; ++s) {
    if (BF16SRC) {
      if (s < 6) { stage_gl(s + 2); __builtin_amdgcn_sched_barrier(0); }
    } else {
      stage_reg(s);
      __syncthreads();
    }
    const char* cb = (const char*)Slds + (s % 3)*16384;
    KSTEP(bA, 0); KSTEP(bB, 1); KSTEP(bC, 2); KSTEP(bD, 3);
    if (BF16SRC) {
      // allow everything issued since stage(s+1): prev-phase B (16) +
      // this phase (4 stage + 16 B) = 36; phase 6: 16+16 = 32; phase 7: none.
      if (s < 6)       PHASE_BARRIER(36);
      else if (s == 6) PHASE_BARRIER(32);
    } else {
      __syncthreads();
    }
  }
#undef KSTEP

  if (!isV) {
    // K-proj: tanh, dot with Q over 64 k-cols, reduce -> logit per row
    const float* Qb = Q + ((size_t)b*H_ + h)*DK_;
    float q[4];
    #pragma unroll
    for (int cc = 0; cc < 4; ++cc) q[cc] = Qb[16*cc + llo];
    #pragma unroll
    for (int rt = 0; rt < 4; ++rt) {
      #pragma unroll
      for (int r = 0; r < 4; ++r) {
        float pl = q[0]*tanh_fast(acc[rt][0][r]) + q[1]*tanh_fast(acc[rt][1][r])
                 + q[2]*tanh_fast(acc[rt][2][r]) + q[3]*tanh_fast(acc[rt][3][r]);
        pl += __shfl_xor(pl, 1); pl += __shfl_xor(pl, 2);
        pl += __shfl_xor(pl, 4); pl += __shfl_xor(pl, 8);
        if (llo == 0) lpart[hp][rt*16 + lhi*4 + r] = pl;
      }
    }
  } else {
    // V-proj: gelu (erf via A&S 7.1.26) in place
    #pragma unroll
    for (int rt = 0; rt < 4; ++rt)
      #pragma unroll
      for (int cc = 0; cc < 4; ++cc)
        #pragma unroll
        for (int r = 0; r < 4; ++r) {
          float x = acc[rt][cc][r];
          acc[rt][cc][r] = 0.5f*x*(1.f + erf_fast(x*0.70710678118654752f));
        }
  }
  __syncthreads();

  if (isV) {
    // softmax stats over this tile's 64 rows (lane <-> row)
    float lg = lpart[hp][lane] * 0.125f;   // 1/sqrt(64)
    float mx = lg;
    #pragma unroll
    for (int mk = 1; mk < 64; mk <<= 1) mx = fmaxf(mx, __shfl_xor(mx, mk));
    float ev = __expf(lg - mx);
    float sv = ev;
    #pragma unroll
    for (int mk = 1; mk < 64; mk <<= 1) sv += __shfl_xor(sv, mk);

    float er[16];
    #pragma unroll
    for (int rt = 0; rt < 4; ++rt)
      #pragma unroll
      for (int r = 0; r < 4; ++r)
        er[rt*4 + r] = __shfl(ev, rt*16 + lhi*4 + r);

    float* pt = part + (((size_t)b*H_ + h)*NT + t)*PSTRIDE;
    #pragma unroll
    for (int cc = 0; cc < 4; ++cc) {
      float y = 0.f;
      #pragma unroll
      for (int rt = 0; rt < 4; ++rt)
        #pragma unroll
        for (int r = 0; r < 4; ++r)
          y += er[rt*4 + r]*acc[rt][cc][r];
      y += __shfl_xor(y, 16); y += __shfl_xor(y, 32);
      if (lhi == 0) pt[2 + 16*cc + llo] = y;
    }
    if (lane == 0) { pt[0] = mx; pt[1] = sv; }
  }
}

// merge NT tile-partials per (b,h); grid (H, B), block 64
__global__ void finalize_kernel(const float* __restrict__ part,
                                float* __restrict__ out) {
  const int h = blockIdx.x, b = blockIdx.y, v = threadIdx.x;
  const float* p = part + ((size_t)b*H_ + h)*(size_t)NT*PSTRIDE;
  float M = -3.0e38f;
  for (int tt = 0; tt < NT; ++tt) M = fmaxf(M, p[tt*PSTRIDE]);
  float ss = 0.f, y = 0.f;
  for (int tt = 0; tt < NT; ++tt) {
    float w = expf(p[tt*PSTRIDE] - M);
    ss += w*p[tt*PSTRIDE + 1];
    y  += w*p[tt*PSTRIDE + 2 + v];
  }
  out[((size_t)b*H_ + h)*DV_ + v] = y/ss;
}

extern "C" void kernel_launch(void* const* d_in, const int* in_sizes, int n_in,
                              void* d_out, int out_size, void* d_ws, size_t ws_size,
                              hipStream_t stream) {
  const float* X  = (const float*)d_in[0];
  const float* S  = (const float*)d_in[1];
  const float* Wq = (const float*)d_in[2];
  const float* Wk = (const float*)d_in[3];
  const float* Wv = (const float*)d_in[4];
  float* out = (float*)d_out;

  char* ws = (char*)d_ws;
  u16*   Wc    = (u16*)ws;                              // 4 MiB
  float* Qbuf  = (float*)(ws + (4u<<20));               // 128 KiB
  float* part  = (float*)(ws + (4u<<20) + (128u<<10));  // ~4.3 MiB
  u16*   Sb    = (u16*)(ws + (16u<<20));                // 128 MiB (optional)
  const bool useBf = ws_size >= (144ull << 20);

  pack_w_kernel  <<<dim3(H_, 128),  256, 0, stream>>>(Wk, Wv, Wc);
  q_proj_kernel  <<<dim3(H_, B_/4), 256, 0, stream>>>(X, Wq, Qbuf);
  if (useBf) {
    s2bf_kernel       <<<dim3(4096), 256, 0, stream>>>(S, Sb);
    fused_kernel<1>   <<<dim3(8192), 256, 0, stream>>>(S, Sb, Wc, Qbuf, part);
  } else {
    fused_kernel<0>   <<<dim3(8192), 256, 0, stream>>>(S, Sb, Wc, Qbuf, part);
  }
  finalize_kernel<<<dim3(H_, B_),    64, 0, stream>>>(part, out);
}